// Round 1
// baseline (196.991 us; speedup 1.0000x reference)
//
#include <hip/hip_runtime.h>

// GAT: B=256, N=64, K=12, D=128
// Algebraic reduction: q/k projections fold into effective vectors
//   wq_eff = Wq @ wa_q, wk_eff = Wk @ wa_k  (since only q.wa_q / k.wa_k are used)
// and the V projection commutes with the attention average:
//   out = (sum_j attn_j nh_j) @ Wv + bv * (sum_j attn_j)
// Total FLOPs drop 14.5G -> 0.65G; kernel becomes HBM-bound on the
// 100.7 MB neighbors_hidden read (~19us roofline).

#define B_  256
#define N_  64
#define K_  12
#define D_  128
#define BN  (B_ * N_)          // 16384 (b,n) pairs

// ws float layout:
//   [0..127]    wq_eff
//   [128..255]  wk_eff
//   [256]       cq  = bq . wa_q
//   [257]       ckb = bk . wa_k
//   [512 .. 512+BN*D)   h_bar  (attention-pooled hidden, row-major [BN][D])
//   [512+BN*D .. +BN)   scale  (= S/(S+1e-16) per pair)
#define WS_HBAR   512
#define WS_SCALE  (512 + BN * D_)

// ---------------------------------------------------------------------------
// Kernel 0: effective attention vectors + scalar constants.
// grid = 258 blocks x 64 threads; one wave per row-reduction task.
//   g < 128   : wq_eff[g]      = Wq[g,:] . wa_q
//   g < 256   : wk_eff[g-128]  = Wk[g-128,:] . wa_k
//   g == 256  : cq  = bq . wa_q
//   g == 257  : ckb = bk . wa_k
__global__ void prep_kernel(const float* __restrict__ Wq, const float* __restrict__ bq,
                            const float* __restrict__ Wk, const float* __restrict__ bk,
                            const float* __restrict__ wa_q, const float* __restrict__ wa_k,
                            float* __restrict__ ws) {
    int g = blockIdx.x;
    int l = threadIdx.x;            // 0..63, lane owns elements 2l, 2l+1
    const float* row;
    const float* wa;
    float* outp;
    if (g < 128)      { row = Wq + g * D_;         wa = wa_q; outp = ws + g; }
    else if (g < 256) { row = Wk + (g - 128) * D_; wa = wa_k; outp = ws + 128 + (g - 128); }
    else if (g == 256){ row = bq;                  wa = wa_q; outp = ws + 256; }
    else              { row = bk;                  wa = wa_k; outp = ws + 257; }

    float2 r = ((const float2*)row)[l];
    float2 w = ((const float2*)wa)[l];
    float p = r.x * w.x + r.y * w.y;
    #pragma unroll
    for (int m = 1; m < 64; m <<= 1) p += __shfl_xor(p, m, 64);
    if (l == 0) *outp = p;
}

// ---------------------------------------------------------------------------
// Kernel 1: fused attention-score + pooling. One wave per (b,n) pair.
// grid = BN/4 blocks x 256 threads (4 waves/block).
// Lane l owns features d=2l,2l+1 (float2 loads, coalesced 512B/wave/vector).
__global__ void __launch_bounds__(256)
attn_kernel(const float* __restrict__ nodes, const float* __restrict__ neigh,
            const float* __restrict__ mask, const float* __restrict__ ba_p,
            float* __restrict__ ws) {
    const int wave = threadIdx.x >> 6;
    const int l    = threadIdx.x & 63;
    const int idx  = blockIdx.x * 4 + wave;      // (b,n) flat index, < BN

    const float cq  = ws[256];
    const float ckb = ws[257];
    const float ba  = ba_p[0];
    float2 wqe = ((const float2*)ws)[l];          // wq_eff
    float2 wke = ((const float2*)(ws + 128))[l];  // wk_eff

    const float2* np = (const float2*)(nodes + (size_t)idx * D_);
    const float2* gp = (const float2*)(neigh + (size_t)idx * K_ * D_);

    // x[0] = node itself (slot prepended in reference), x[1..12] = neighbors
    float2 x[K_ + 1];
    x[0] = np[l];
    #pragma unroll
    for (int j = 0; j < K_; ++j) x[j + 1] = gp[j * 64 + l];

    float mval = (l < K_) ? mask[(size_t)idx * K_ + l] : 0.0f;

    // per-lane partial dot products
    float pq = x[0].x * wqe.x + x[0].y * wqe.y;
    float pk[K_ + 1];
    #pragma unroll
    for (int j = 0; j <= K_; ++j) pk[j] = x[j].x * wke.x + x[j].y * wke.y;

    // 14 wave reductions (butterfly); all lanes end with the full sums
    #pragma unroll
    for (int m = 1; m < 64; m <<= 1) {
        pq += __shfl_xor(pq, m, 64);
        #pragma unroll
        for (int j = 0; j <= K_; ++j) pk[j] += __shfl_xor(pk[j], m, 64);
    }

    const float aq = pq + cq;
    float e[K_ + 1];
    float S = 0.0f;
    #pragma unroll
    for (int j = 0; j <= K_; ++j) {
        float s = aq + pk[j] + ckb + ba;
        s = (s >= 0.0f) ? s : 0.2f * s;          // LeakyReLU(0.2)
        float mj = (j == 0) ? 1.0f : __shfl(mval, j - 1, 64);
        e[j] = expf(s) * mj;                      // masked exp (matches torch)
        S += e[j];
    }
    const float inv = 1.0f / (S + 1e-16f);

    float h0 = 0.0f, h1 = 0.0f;
    #pragma unroll
    for (int j = 0; j <= K_; ++j) {
        float w = e[j] * inv;
        h0 += w * x[j].x;
        h1 += w * x[j].y;
    }

    float2* hb = (float2*)(ws + WS_HBAR) + (size_t)idx * (D_ / 2);
    hb[l] = make_float2(h0, h1);
    if (l == 0) ws[WS_SCALE + idx] = S * inv;     // sum of attn weights
}

// ---------------------------------------------------------------------------
// Kernel 2: out = h_bar @ Wv + bv * scale.  [16384,128] @ [128,128].
// grid = BN/32 blocks x 256 threads; 32 rows/block.
// Thread (rg=t>>5, cg=t&31) computes rows rg*4..+3, cols cg*4..+3 (16 acc).
// hb tile in LDS with stride 132 (a-reads are <=2 distinct addrs/wave: free).
// Wv rows streamed from global (L1/L2-resident, 64KB).
#define HB_STRIDE 132
__global__ void __launch_bounds__(256)
gemm_kernel(const float* __restrict__ ws, const float* __restrict__ Wv,
            const float* __restrict__ bv, float* __restrict__ out) {
    __shared__ float hb[32 * HB_STRIDE];
    __shared__ float scL[32];

    const int t    = threadIdx.x;
    const int row0 = blockIdx.x * 32;
    const float* hbar  = ws + WS_HBAR;
    const float* scale = ws + WS_SCALE;

    // stage 32x128 h_bar tile (coalesced float4 loads)
    #pragma unroll
    for (int i = 0; i < 4; ++i) {
        int idx = (i * 256 + t) * 4;              // 0..16383 in steps of 4
        int row = idx >> 7;
        int k   = idx & 127;
        float4 v = *(const float4*)(hbar + (size_t)(row0 + row) * D_ + k);
        *(float4*)(hb + row * HB_STRIDE + k) = v;
    }
    if (t < 32) scL[t] = scale[row0 + t];
    __syncthreads();

    const int rg = t >> 5;                        // 0..7 -> rows rg*4..+3
    const int cg = t & 31;                        // cols cg*4..+3
    const float4* wv4 = (const float4*)Wv;        // [k][32] of float4

    float acc[4][4];
    #pragma unroll
    for (int i = 0; i < 4; ++i)
        #pragma unroll
        for (int c = 0; c < 4; ++c) acc[i][c] = 0.0f;

    #pragma unroll 8
    for (int k = 0; k < D_; ++k) {
        float4 b = wv4[k * 32 + cg];
        #pragma unroll
        for (int i = 0; i < 4; ++i) {
            float a = hb[(rg * 4 + i) * HB_STRIDE + k];
            acc[i][0] += a * b.x;
            acc[i][1] += a * b.y;
            acc[i][2] += a * b.z;
            acc[i][3] += a * b.w;
        }
    }

    float4 bvv = ((const float4*)bv)[cg];
    #pragma unroll
    for (int i = 0; i < 4; ++i) {
        float s = scL[rg * 4 + i];
        float4 o;
        o.x = acc[i][0] + bvv.x * s;
        o.y = acc[i][1] + bvv.y * s;
        o.z = acc[i][2] + bvv.z * s;
        o.w = acc[i][3] + bvv.w * s;
        *(float4*)(out + (size_t)(row0 + rg * 4 + i) * D_ + cg * 4) = o;
    }
}

// ---------------------------------------------------------------------------
extern "C" void kernel_launch(void* const* d_in, const int* in_sizes, int n_in,
                              void* d_out, int out_size, void* d_ws, size_t ws_size,
                              hipStream_t stream) {
    const float* nodes = (const float*)d_in[0];
    const float* neigh = (const float*)d_in[1];
    const float* mask  = (const float*)d_in[2];
    const float* Wq    = (const float*)d_in[3];
    const float* bq    = (const float*)d_in[4];
    const float* Wk    = (const float*)d_in[5];
    const float* bk    = (const float*)d_in[6];
    const float* Wv    = (const float*)d_in[7];
    const float* bv    = (const float*)d_in[8];
    const float* wa_q  = (const float*)d_in[9];
    const float* wa_k  = (const float*)d_in[10];
    const float* ba    = (const float*)d_in[11];
    float* out = (float*)d_out;
    float* ws  = (float*)d_ws;

    prep_kernel<<<258, 64, 0, stream>>>(Wq, bq, Wk, bk, wa_q, wa_k, ws);
    attn_kernel<<<BN / 4, 256, 0, stream>>>(nodes, neigh, mask, ba, ws);
    gemm_kernel<<<BN / 32, 256, 0, stream>>>(ws, Wv, bv, out);
}

// Round 2
// 187.536 us; speedup vs baseline: 1.0504x; 1.0504x over previous
//
#include <hip/hip_runtime.h>

// GAT: B=256, N=64, K=12, D=128
// Algebraic reduction: q/k projections fold into effective vectors
//   wq_eff = Wq @ wa_q, wk_eff = Wk @ wa_k  (only q.wa_q / k.wa_k are used)
// and the V projection commutes with the attention average:
//   out = (sum_j attn_j nh_j) @ Wv + bv * (sum_j attn_j)
// FLOPs drop 14.5G -> 0.65G; HBM-bound on the 100.7 MB neighbors read.
//
// R1: fuse attn+gemm into ONE kernel (block owns 32 pairs: attention phase
// writes h_bar straight into the LDS tile, then the 32x128 @ 128x128 matvec)
// -- removes the 16 MB h_bar ws round-trip, one launch gap, and gemm's
// staging pass. expf -> __expf (native v_exp_f32).

#define B_  256
#define N_  64
#define K_  12
#define D_  128
#define BN  (B_ * N_)          // 16384 (b,n) pairs

// ws float layout: [0..127] wq_eff | [128..255] wk_eff | [256] cq | [257] ckb
// ---------------------------------------------------------------------------
// Kernel 0: effective attention vectors + scalar constants.
__global__ void prep_kernel(const float* __restrict__ Wq, const float* __restrict__ bq,
                            const float* __restrict__ Wk, const float* __restrict__ bk,
                            const float* __restrict__ wa_q, const float* __restrict__ wa_k,
                            float* __restrict__ ws) {
    int g = blockIdx.x;
    int l = threadIdx.x;            // 0..63, lane owns elements 2l, 2l+1
    const float* row;
    const float* wa;
    float* outp;
    if (g < 128)      { row = Wq + g * D_;         wa = wa_q; outp = ws + g; }
    else if (g < 256) { row = Wk + (g - 128) * D_; wa = wa_k; outp = ws + 128 + (g - 128); }
    else if (g == 256){ row = bq;                  wa = wa_q; outp = ws + 256; }
    else              { row = bk;                  wa = wa_k; outp = ws + 257; }

    float2 r = ((const float2*)row)[l];
    float2 w = ((const float2*)wa)[l];
    float p = r.x * w.x + r.y * w.y;
    #pragma unroll
    for (int m = 1; m < 64; m <<= 1) p += __shfl_xor(p, m, 64);
    if (l == 0) *outp = p;
}

// ---------------------------------------------------------------------------
// Kernel 1 (fused): attention-score + pooling + V-projection.
// grid = BN/32 = 512 blocks x 256 threads. Block owns 32 (b,n) pairs.
// Phase A: wave w computes attention for pairs w*8..w*8+7 (one at a time,
//          lane l owns features 2l,2l+1), h_bar row -> LDS tile.
// Phase B: 32x128 tile @ Wv[128x128]: thread (rg=t>>5,cg=t&31) does a 4x4
//          register block; hb LDS stride 132 => a-reads 2 distinct banks: free.
#define HB_STRIDE 132
__global__ void __launch_bounds__(256)
fused_kernel(const float* __restrict__ nodes, const float* __restrict__ neigh,
             const float* __restrict__ mask, const float* __restrict__ ba_p,
             const float* __restrict__ ws, const float* __restrict__ Wv,
             const float* __restrict__ bv, float* __restrict__ out) {
    __shared__ float hb[32 * HB_STRIDE];
    __shared__ float scL[32];

    const int t    = threadIdx.x;
    const int wave = t >> 6;
    const int l    = t & 63;

    const float cq  = ws[256];
    const float ckb = ws[257];
    const float ba  = ba_p[0];
    const float cst = cq + ckb + ba;              // constant part of every score
    float2 wqe = ((const float2*)ws)[l];          // wq_eff
    float2 wke = ((const float2*)(ws + 128))[l];  // wk_eff

    // ---- Phase A: attention for this wave's 8 pairs ----
    for (int p = 0; p < 8; ++p) {
        const int lrow = wave * 8 + p;                 // 0..31 local row
        const int idx  = blockIdx.x * 32 + lrow;       // (b,n) flat index

        const float2* np = (const float2*)(nodes + (size_t)idx * D_);
        const float2* gp = (const float2*)(neigh + (size_t)idx * K_ * D_);

        // x[0] = node itself (prepended slot), x[1..12] = neighbors
        float2 x[K_ + 1];
        x[0] = np[l];
        #pragma unroll
        for (int j = 0; j < K_; ++j) x[j + 1] = gp[j * 64 + l];

        float mval = (l < K_) ? mask[(size_t)idx * K_ + l] : 0.0f;

        // per-lane partial dot products
        float pq = x[0].x * wqe.x + x[0].y * wqe.y;
        float pk[K_ + 1];
        #pragma unroll
        for (int j = 0; j <= K_; ++j) pk[j] = x[j].x * wke.x + x[j].y * wke.y;

        // 14 wave butterfly reductions; all lanes end with full sums
        #pragma unroll
        for (int m = 1; m < 64; m <<= 1) {
            pq += __shfl_xor(pq, m, 64);
            #pragma unroll
            for (int j = 0; j <= K_; ++j) pk[j] += __shfl_xor(pk[j], m, 64);
        }

        const float base = pq + cst;
        float e[K_ + 1];
        float S = 0.0f;
        #pragma unroll
        for (int j = 0; j <= K_; ++j) {
            float s = base + pk[j];
            s = (s >= 0.0f) ? s : 0.2f * s;           // LeakyReLU(0.2)
            float mj = (j == 0) ? 1.0f : __shfl(mval, j - 1, 64);
            e[j] = __expf(s) * mj;                    // masked exp
            S += e[j];
        }
        const float inv = 1.0f / (S + 1e-16f);

        float h0 = 0.0f, h1 = 0.0f;
        #pragma unroll
        for (int j = 0; j <= K_; ++j) {
            float w = e[j] * inv;
            h0 += w * x[j].x;
            h1 += w * x[j].y;
        }

        *(float2*)(hb + lrow * HB_STRIDE + 2 * l) = make_float2(h0, h1);
        if (l == 0) scL[lrow] = S * inv;              // sum of attn weights
    }
    __syncthreads();

    // ---- Phase B: out[32x128] = hb @ Wv + bv * scale ----
    const int rg = t >> 5;                        // 0..7 -> rows rg*4..+3
    const int cg = t & 31;                        // cols cg*4..+3
    const int row0 = blockIdx.x * 32;
    const float4* wv4 = (const float4*)Wv;        // [k][32] of float4

    float acc[4][4];
    #pragma unroll
    for (int i = 0; i < 4; ++i)
        #pragma unroll
        for (int c = 0; c < 4; ++c) acc[i][c] = 0.0f;

    #pragma unroll 8
    for (int k = 0; k < D_; ++k) {
        float4 b = wv4[k * 32 + cg];
        #pragma unroll
        for (int i = 0; i < 4; ++i) {
            float a = hb[(rg * 4 + i) * HB_STRIDE + k];
            acc[i][0] += a * b.x;
            acc[i][1] += a * b.y;
            acc[i][2] += a * b.z;
            acc[i][3] += a * b.w;
        }
    }

    float4 bvv = ((const float4*)bv)[cg];
    #pragma unroll
    for (int i = 0; i < 4; ++i) {
        float s = scL[rg * 4 + i];
        float4 o;
        o.x = acc[i][0] + bvv.x * s;
        o.y = acc[i][1] + bvv.y * s;
        o.z = acc[i][2] + bvv.z * s;
        o.w = acc[i][3] + bvv.w * s;
        *(float4*)(out + (size_t)(row0 + rg * 4 + i) * D_ + cg * 4) = o;
    }
}

// ---------------------------------------------------------------------------
extern "C" void kernel_launch(void* const* d_in, const int* in_sizes, int n_in,
                              void* d_out, int out_size, void* d_ws, size_t ws_size,
                              hipStream_t stream) {
    const float* nodes = (const float*)d_in[0];
    const float* neigh = (const float*)d_in[1];
    const float* mask  = (const float*)d_in[2];
    const float* Wq    = (const float*)d_in[3];
    const float* bq    = (const float*)d_in[4];
    const float* Wk    = (const float*)d_in[5];
    const float* bk    = (const float*)d_in[6];
    const float* Wv    = (const float*)d_in[7];
    const float* bv    = (const float*)d_in[8];
    const float* wa_q  = (const float*)d_in[9];
    const float* wa_k  = (const float*)d_in[10];
    const float* ba    = (const float*)d_in[11];
    float* out = (float*)d_out;
    float* ws  = (float*)d_ws;

    prep_kernel<<<258, 64, 0, stream>>>(Wq, bq, Wk, bk, wa_q, wa_k, ws);
    fused_kernel<<<BN / 32, 256, 0, stream>>>(nodes, neigh, mask, ba, ws, Wv, bv, out);
}